// Round 3
// baseline (2912.261 us; speedup 1.0000x reference)
//
#include <hip/hip_runtime.h>
#include <math.h>

#define NN 8192
#define NE 131072
#define NKT 125

typedef __attribute__((ext_vector_type(8))) short bf16x8;
typedef __attribute__((ext_vector_type(4))) float f32x4;

__device__ inline unsigned short bf16rne(float v){
  unsigned u = __float_as_uint(v);
  u += 0x7FFF + ((u>>16)&1);
  return (unsigned short)(u>>16);
}

__device__ inline void splitpack8(const f32x4& a0, const f32x4& a1, bf16x8& h, bf16x8& l){
  #pragma unroll
  for (int u=0;u<4;u++){
    unsigned short hh = bf16rne(a0[u]);
    h[u] = (short)hh;
    l[u] = (short)bf16rne(a0[u] - __uint_as_float((unsigned)hh<<16));
  }
  #pragma unroll
  for (int u=0;u<4;u++){
    unsigned short hh = bf16rne(a1[u]);
    h[u+4] = (short)hh;
    l[u+4] = (short)bf16rne(a1[u] - __uint_as_float((unsigned)hh<<16));
  }
}

// ---------------- basis ----------------
__global__ void k_basis(const float* __restrict__ pseudo,
                        float* __restrict__ basis, int* __restrict__ kidx) {
  int e = blockIdx.x * 256 + threadIdx.x;
  if (e >= NE) return;
  float s0 = pseudo[e*3+0]*4.f, s1 = pseudo[e*3+1]*4.f, s2 = pseudo[e*3+2]*4.f;
  float f0 = floorf(s0), f1 = floorf(s1), f2 = floorf(s2);
  int l0=(int)f0, l1=(int)f1, l2=(int)f2;
  float r0=s0-f0, r1=s1-f1, r2=s2-f2;
  #pragma unroll
  for (int s=0;s<8;s++){
    int b0=s&1, b1=(s>>1)&1, b2=(s>>2)&1;
    int i0=min(max(l0+b0,0),4);
    int i1=min(max(l1+b1,0),4);
    int i2=min(max(l2+b2,0),4);
    float w=(b0? r0:1.f-r0)*(b1? r1:1.f-r1)*(b2? r2:1.f-r2);
    basis[e*8+s]=w;
    kidx[e*8+s]=i0+5*i1+25*i2;
  }
}

// ---------------- counting sort by dst (layer-1 path) ----------------
__global__ void k_hist(const int* __restrict__ dst, int* __restrict__ counts) {
  int e = blockIdx.x*256 + threadIdx.x;
  if (e >= NE) return;
  atomicAdd(&counts[dst[e]], 1);
}

__global__ void k_scan(const int* __restrict__ counts, int* __restrict__ offs,
                       int* __restrict__ cursor) {
  __shared__ int lds[1024];
  int t = threadIdx.x;
  int base = t*8;
  int c[8]; int s = 0;
  #pragma unroll
  for (int j=0;j<8;j++){ c[j]=counts[base+j]; s+=c[j]; }
  lds[t]=s; __syncthreads();
  for (int o=1;o<1024;o<<=1){
    int v = (t>=o)? lds[t-o] : 0;
    __syncthreads();
    lds[t]+=v;
    __syncthreads();
  }
  int run = (t==0)? 0 : lds[t-1];
  #pragma unroll
  for (int j=0;j<8;j++){ offs[base+j]=run; cursor[base+j]=run; run+=c[j]; }
  if (t==1023) offs[NN]=run;
}

__global__ void k_place(const int* __restrict__ dst, int* __restrict__ cursor,
                        int* __restrict__ sorted) {
  int e = blockIdx.x*256 + threadIdx.x;
  if (e >= NE) return;
  int p = atomicAdd(&cursor[dst[e]], 1);
  sorted[p] = e;
}

// ---------------- pair sort by (dst>>7, kidx): 8000 buckets over 1M pairs ----
__global__ void k_phist(const int* __restrict__ dst, const int* __restrict__ kidx,
                        int* __restrict__ cnt){
  int e = blockIdx.x*256 + threadIdx.x;
  if (e>=NE) return;
  int kb = (dst[e]>>7)*NKT;
  #pragma unroll
  for (int c=0;c<8;c++) atomicAdd(&cnt[kb + kidx[e*8+c]], 1);
}

__global__ void k_pscan(const int* __restrict__ cnt, int* __restrict__ offs,
                        int* __restrict__ cur){
  __shared__ int lds[1024];
  int t=threadIdx.x, base=t*8;
  int c[8]; int s=0;
  #pragma unroll
  for (int j=0;j<8;j++){ int v = (base+j<8000)? cnt[base+j] : 0; c[j]=v; s+=v; }
  lds[t]=s; __syncthreads();
  for (int o=1;o<1024;o<<=1){
    int v=(t>=o)?lds[t-o]:0;
    __syncthreads();
    lds[t]+=v;
    __syncthreads();
  }
  int run=(t==0)?0:lds[t-1];
  #pragma unroll
  for (int j=0;j<8;j++){
    if (base+j<=8000){ offs[base+j]=run; cur[base+j]=run; }
    run+=c[j];
  }
}

__global__ void k_pplace(const int* __restrict__ src, const int* __restrict__ dst,
                         const float* __restrict__ basis, const int* __restrict__ kidx,
                         int* __restrict__ cur, uint2* __restrict__ pairs){
  int e = blockIdx.x*256 + threadIdx.x;
  if (e>=NE) return;
  int d = dst[e];
  unsigned a = (unsigned)src[e] | ((unsigned)(d&127)<<16);
  int kb = (d>>7)*NKT;
  #pragma unroll
  for (int c=0;c<8;c++){
    int p = atomicAdd(&cur[kb + kidx[e*8+c]], 1);
    pairs[p] = make_uint2(a, __float_as_uint(basis[e*8+c]));
  }
}

// ---------------- W prep: [125][CIN][64] fp32 -> transposed split bf16 [125][64][CIN]
template<int CIN>
__global__ void k_wprep(const float* __restrict__ W, unsigned short* __restrict__ Whi,
                        unsigned short* __restrict__ Wlo){
  int k = blockIdx.x; int t = threadIdx.x;
  const float* Wk = W + (size_t)k*CIN*64;
  unsigned short* Hk = Whi + (size_t)k*64*CIN;
  unsigned short* Lk = Wlo + (size_t)k*64*CIN;
  for (int idx=t; idx<CIN*64; idx+=256){
    int o = idx/CIN, i = idx - o*CIN;
    float v = Wk[i*64 + o];
    unsigned short h = bf16rne(v);
    Hk[idx] = h;
    Lk[idx] = bf16rne(v - __uint_as_float((unsigned)h<<16));
  }
}

// ---------------- fused build+GEMM conv: out partials = scatter(M)@W on the fly
// grid (64 row-blocks, 8 K-slices). Per kernel cell: LDS fp32 tile [128][TK]
// (XOR-swizzled), wave-atomic pair accumulation, split-bf16 MFMA vs W_k (regs).
template<int TK>   // TK == CIN in {32,64}
__global__ __launch_bounds__(256) void k_fconv(const float* __restrict__ x,
    const unsigned short* __restrict__ Whi, const unsigned short* __restrict__ Wlo,
    const uint2* __restrict__ pairs, const int* __restrict__ poff,
    float* __restrict__ Cp) {
  constexpr int KK = TK/32;
  __shared__ float Afp[128*TK];
  int t = threadIdx.x, w = t>>6, lane = t&63;
  int lr = lane&15, kq = lane>>4;
  int rb = blockIdx.x;
  int s  = blockIdx.y;
  int t0 = s*16, t1 = min(NKT, t0+16);
  int wrow = w*32;

  f32x4 acc[2][4];
  #pragma unroll
  for (int i=0;i<2;i++)
    #pragma unroll
    for (int j=0;j<4;j++) acc[i][j] = (f32x4){0.f,0.f,0.f,0.f};

  for (int tile=t0; tile<t1; ++tile) {
    // zero the fp32 accumulation tile
    #pragma unroll
    for (int q=0;q<(128*TK)/(4*256);q++)
      *(f32x4*)&Afp[(t + q*256)*4] = (f32x4){0.f,0.f,0.f,0.f};
    // issue W-fragment loads (L2-resident) — in flight during the pair phase
    bf16x8 wh[KK][4], wl[KK][4];
    const unsigned short* wb  = Whi + (size_t)tile*64*TK;
    const unsigned short* wlb = Wlo + (size_t)tile*64*TK;
    #pragma unroll
    for (int kk=0;kk<KK;kk++)
      #pragma unroll
      for (int fn=0;fn<4;fn++){
        int off = (fn*16+lr)*TK + kk*32 + kq*8;
        wh[kk][fn] = *(const bf16x8*)(wb + off);
        wl[kk][fn] = *(const bf16x8*)(wlb + off);
      }
    __syncthreads();
    // pair accumulation phase
    int bkey = rb*NKT + tile;
    int r0 = poff[bkey], r1 = poff[bkey+1];
    if constexpr (TK==64) {
      for (int j=r0+w; j<r1; j+=4) {
        uint2 p = pairs[j];
        int srcn = p.x & 0xffff, row = (p.x>>16)&0x7f;
        float bas = __uint_as_float(p.y);
        float xv = x[srcn*64 + lane];
        int ea = (row*64 + lane) ^ ((row&7)<<2);
        atomicAdd(&Afp[ea], bas*xv);
      }
    } else {
      int ln = lane&31, half = lane>>5;
      for (int j=r0+w*2+half; j<r1; j+=8) {
        uint2 p = pairs[j];
        int srcn = p.x & 0xffff, row = (p.x>>16)&0x7f;
        float bas = __uint_as_float(p.y);
        float xv = x[srcn*32 + ln];
        int ea = (row*32 + ln) ^ ((row&7)<<2);
        atomicAdd(&Afp[ea], bas*xv);
      }
    }
    __syncthreads();
    // MFMA phase: split-bf16 A from LDS, W from regs
    #pragma unroll
    for (int kk=0;kk<KK;kk++){
      #pragma unroll
      for (int fm=0;fm<2;fm++){
        int row = wrow + fm*16 + lr;
        int e0 = row*TK + kk*32 + kq*8;
        int sz = (row&7)<<2;
        f32x4 a0 = *(const f32x4*)&Afp[(e0  )^sz];
        f32x4 a1 = *(const f32x4*)&Afp[(e0+4)^sz];
        bf16x8 ah, al;
        splitpack8(a0, a1, ah, al);
        #pragma unroll
        for (int fn=0;fn<4;fn++){
          acc[fm][fn] = __builtin_amdgcn_mfma_f32_16x16x32_bf16(ah, wh[kk][fn], acc[fm][fn], 0,0,0);
          acc[fm][fn] = __builtin_amdgcn_mfma_f32_16x16x32_bf16(ah, wl[kk][fn], acc[fm][fn], 0,0,0);
          acc[fm][fn] = __builtin_amdgcn_mfma_f32_16x16x32_bf16(al, wh[kk][fn], acc[fm][fn], 0,0,0);
        }
      }
    }
    __syncthreads();
  }
  // epilogue: write split-K partials
  size_t sbase = (size_t)s*NN*64;
  #pragma unroll
  for (int fm=0;fm<2;fm++)
    #pragma unroll
    for (int fn=0;fn<4;fn++)
      #pragma unroll
      for (int r=0;r<4;r++){
        int row = rb*128 + wrow + fm*16 + kq*4 + r;
        Cp[sbase + (size_t)row*64 + fn*16 + lr] = acc[fm][fn][r];
      }
}

// ---------------- build M rows, layer 1 only ----------------
template<int CIN>
__global__ void k_build(const float* __restrict__ x,
                        const float* __restrict__ basis, const int* __restrict__ kidx,
                        const int* __restrict__ src, const int* __restrict__ sorted,
                        const int* __restrict__ offs, float* __restrict__ M, int lda) {
  constexpr int SZ = NKT*CIN;
  __shared__ float acc[SZ];
  int n = blockIdx.x, t = threadIdx.x;
  for (int i=t;i<SZ;i+=256) acc[i]=0.f;
  __syncthreads();
  int beg = offs[n], end = offs[n+1];
  int wv = t>>6, ln = t&63;
  for (int j=beg+wv; j<end; j+=4) {
    int e = sorted[j];
    int sv = src[e];
    float xv = (ln<CIN)? x[(size_t)sv*CIN+ln] : 0.f;
    #pragma unroll
    for (int c=0;c<8;c++){
      float b = basis[e*8+c];
      int k = kidx[e*8+c];
      if (ln<CIN) atomicAdd(&acc[k*CIN+ln], b*xv);
    }
  }
  __syncthreads();
  size_t base = (size_t)n*lda;
  for (int i=t;i<lda;i+=256) M[base+i] = (i<SZ)? acc[i] : 0.f;
}

// ---------------- root weight + bias ----------------
template<int CIN,int COUT>
__global__ void k_root(const float* __restrict__ x, const float* __restrict__ R,
                       const float* __restrict__ B, float* __restrict__ C) {
  int n = blockIdx.x, o = threadIdx.x;
  float s = B[o];
  #pragma unroll 8
  for (int i=0;i<CIN;i++) s += x[(size_t)n*CIN+i]*R[i*COUT+o];
  C[(size_t)n*COUT+o] = s;
}

// ---------------- conv GEMM (layer 1 only), split-bf16 MFMA ----------------
template<int BN>
__global__ __launch_bounds__(256) void k_gconv(const float* __restrict__ A,
                                               const float* __restrict__ B,
                                               float* __restrict__ Cp,
                                               int K, int lda, int nsl) {
  __shared__ alignas(16) char smem[2*128*128 + 2*BN*128];
  char* Ahp = smem;
  char* Alp = smem + 128*128;
  char* Bhp = smem + 2*128*128;
  char* Blp = Bhp + BN*128;

  int t = threadIdx.x;
  int w = t>>6, lane = t&63;
  int lr = lane & 15, kq = lane >> 4;
  int rb = blockIdx.x*128;
  int sl = blockIdx.y;
  int len = ((K + nsl - 1)/nsl + 63) & ~63;
  int kbeg = sl*len;
  int kend = min(K, kbeg + len);

  f32x4 acc[2][BN/16];
  #pragma unroll
  for (int i=0;i<2;i++)
    #pragma unroll
    for (int j=0;j<BN/16;j++) acc[i][j] = (f32x4){0.f,0.f,0.f,0.f};

  for (int k0 = kbeg; k0 < kend; k0 += 64) {
    #pragma unroll
    for (int q=0;q<8;q++){
      int lin = t + 256*q;
      int row = lin >> 4;
      int f4  = lin & 15;
      int kg = k0 + f4*4;
      const float* ap = A + (size_t)(rb+row)*lda + kg;
      float4 v; v.x=0.f; v.y=0.f; v.z=0.f; v.w=0.f;
      if (kg + 3 < kend) v = *(const float4*)ap;
      else {
        if (kg   < kend) v.x = ap[0];
        if (kg+1 < kend) v.y = ap[1];
        if (kg+2 < kend) v.z = ap[2];
      }
      unsigned short h[4], l[4];
      float vv[4] = {v.x, v.y, v.z, v.w};
      #pragma unroll
      for (int u=0;u<4;u++){
        unsigned short hh = bf16rne(vv[u]);
        float fh = __uint_as_float(((unsigned)hh)<<16);
        h[u]=hh; l[u]=bf16rne(vv[u]-fh);
      }
      int bo = (row*128 + f4*8) ^ ((row&7)<<4);
      *(uint2*)(Ahp + bo) = make_uint2((unsigned)h[0]|((unsigned)h[1]<<16),
                                       (unsigned)h[2]|((unsigned)h[3]<<16));
      *(uint2*)(Alp + bo) = make_uint2((unsigned)l[0]|((unsigned)l[1]<<16),
                                       (unsigned)l[2]|((unsigned)l[3]<<16));
    }
    constexpr int BITER = (64*(BN/4))/256;
    #pragma unroll
    for (int q=0;q<BITER;q++){
      int lin = t + 256*q;
      int kr = lin / (BN/4);
      int c4 = (lin % (BN/4))*4;
      int kg = k0 + kr;
      float4 v; v.x=0.f; v.y=0.f; v.z=0.f; v.w=0.f;
      if (kg < kend) v = *(const float4*)&B[(size_t)kg*BN + c4];
      float vv[4] = {v.x, v.y, v.z, v.w};
      #pragma unroll
      for (int u=0;u<4;u++){
        int n = c4 + u;
        unsigned short hh = bf16rne(vv[u]);
        float fh = __uint_as_float(((unsigned)hh)<<16);
        int bo = (n*128 + kr*2) ^ ((n&7)<<4);
        *(unsigned short*)(Bhp + bo) = hh;
        *(unsigned short*)(Blp + bo) = bf16rne(vv[u]-fh);
      }
    }
    __syncthreads();
    int wrow = w*32;
    #pragma unroll
    for (int kk=0;kk<2;kk++){
      int kbyte = (kk*32 + kq*8)*2;
      bf16x8 ah[2], al[2];
      #pragma unroll
      for (int fm=0;fm<2;fm++){
        int row = wrow + fm*16 + lr;
        int bo = (row*128 + kbyte) ^ ((row&7)<<4);
        ah[fm] = *(const bf16x8*)(Ahp + bo);
        al[fm] = *(const bf16x8*)(Alp + bo);
      }
      #pragma unroll
      for (int fn=0;fn<BN/16;fn++){
        int n = fn*16 + lr;
        int bo = (n*128 + kbyte) ^ ((n&7)<<4);
        bf16x8 bh = *(const bf16x8*)(Bhp + bo);
        bf16x8 bl = *(const bf16x8*)(Blp + bo);
        #pragma unroll
        for (int fm=0;fm<2;fm++){
          acc[fm][fn] = __builtin_amdgcn_mfma_f32_16x16x32_bf16(ah[fm], bh, acc[fm][fn], 0,0,0);
          acc[fm][fn] = __builtin_amdgcn_mfma_f32_16x16x32_bf16(ah[fm], bl, acc[fm][fn], 0,0,0);
          acc[fm][fn] = __builtin_amdgcn_mfma_f32_16x16x32_bf16(al[fm], bh, acc[fm][fn], 0,0,0);
        }
      }
    }
    __syncthreads();
  }
  size_t sbase = (size_t)sl * NN * BN;
  int r0g = rb + w*32;
  #pragma unroll
  for (int fm=0;fm<2;fm++)
    #pragma unroll
    for (int fn=0;fn<BN/16;fn++)
      #pragma unroll
      for (int r=0;r<4;r++){
        int row = r0g + fm*16 + kq*4 + r;
        int col = fn*16 + lr;
        Cp[sbase + (size_t)row*BN + col] = acc[fm][fn][r];
      }
}

// ---------------- reduce split-K partials + root, apply ELU ----------------
__global__ void k_reduce(const float* __restrict__ Cr, const float* __restrict__ Cp,
                         float* __restrict__ H, int total, int nsl) {
  int i = blockIdx.x*256 + threadIdx.x;
  if (i >= total) return;
  float v = Cr[i];
  for (int s=0;s<nsl;s++) v += Cp[(size_t)s*total+i];
  H[i] = v>0.f ? v : expm1f(v);
}

// ---------------- Linear(64,256) + ELU ----------------
__global__ void k_l1(const float* __restrict__ H, const float* __restrict__ Wm,
                     const float* __restrict__ b, float* __restrict__ O) {
  int n = blockIdx.x, o = threadIdx.x;
  float s = b[o];
  #pragma unroll 16
  for (int i=0;i<64;i++) s += H[(size_t)n*64+i]*Wm[i*256+o];
  s = s>0.f ? s : expm1f(s);
  O[(size_t)n*256+o] = s;
}

// ---------------- Linear(256,8192) split-bf16 MFMA + bias + lsm stats ----------
__global__ __launch_bounds__(256) void k_l2m(const float* __restrict__ A,
                                             const float* __restrict__ B,
                                             const float* __restrict__ bias,
                                             float* __restrict__ C,
                                             float* __restrict__ pstats) {
  __shared__ alignas(16) char smem[4*128*128];
  char* Ahp = smem;
  char* Alp = smem + 128*128;
  char* Bhp = smem + 2*128*128;
  char* Blp = smem + 3*128*128;

  int t = threadIdx.x;
  int w = t>>6, lane = t&63;
  int lr = lane & 15, kq = lane >> 4;
  int wr = w>>1, wc = w&1;
  int rb = blockIdx.y*128;
  int cb = blockIdx.x*128;

  f32x4 acc[4][4];
  #pragma unroll
  for (int i=0;i<4;i++)
    #pragma unroll
    for (int j=0;j<4;j++) acc[i][j] = (f32x4){0.f,0.f,0.f,0.f};

  for (int k0=0;k0<256;k0+=64) {
    #pragma unroll
    for (int q=0;q<8;q++){
      int lin = t + 256*q;
      int row = lin >> 4;
      int f4  = lin & 15;
      const float4 v = *(const float4*)&A[(size_t)(rb+row)*256 + k0 + f4*4];
      unsigned short h[4], l[4];
      float vv[4] = {v.x, v.y, v.z, v.w};
      #pragma unroll
      for (int u=0;u<4;u++){
        unsigned short hh = bf16rne(vv[u]);
        float fh = __uint_as_float(((unsigned)hh)<<16);
        h[u]=hh; l[u]=bf16rne(vv[u]-fh);
      }
      int bo = (row*128 + f4*8) ^ ((row&7)<<4);
      *(uint2*)(Ahp + bo) = make_uint2((unsigned)h[0]|((unsigned)h[1]<<16),
                                       (unsigned)h[2]|((unsigned)h[3]<<16));
      *(uint2*)(Alp + bo) = make_uint2((unsigned)l[0]|((unsigned)l[1]<<16),
                                       (unsigned)l[2]|((unsigned)l[3]<<16));
    }
    #pragma unroll
    for (int q=0;q<8;q++){
      int lin = t + 256*q;
      int kr = lin >> 5;
      int c4 = (lin & 31)*4;
      const float4 v = *(const float4*)&B[(size_t)(k0+kr)*8192 + cb + c4];
      float vv[4] = {v.x, v.y, v.z, v.w};
      #pragma unroll
      for (int u=0;u<4;u++){
        int n = c4 + u;
        unsigned short hh = bf16rne(vv[u]);
        float fh = __uint_as_float(((unsigned)hh)<<16);
        int bo = (n*128 + kr*2) ^ ((n&7)<<4);
        *(unsigned short*)(Bhp + bo) = hh;
        *(unsigned short*)(Blp + bo) = bf16rne(vv[u]-fh);
      }
    }
    __syncthreads();
    int wrow = wr*64, wcol = wc*64;
    #pragma unroll
    for (int kk=0;kk<2;kk++){
      int kbyte = (kk*32 + kq*8)*2;
      bf16x8 ah[4], al[4];
      #pragma unroll
      for (int fm=0;fm<4;fm++){
        int row = wrow + fm*16 + lr;
        int bo = (row*128 + kbyte) ^ ((row&7)<<4);
        ah[fm] = *(const bf16x8*)(Ahp + bo);
        al[fm] = *(const bf16x8*)(Alp + bo);
      }
      #pragma unroll
      for (int fn=0;fn<4;fn++){
        int n = wcol + fn*16 + lr;
        int bo = (n*128 + kbyte) ^ ((n&7)<<4);
        bf16x8 bh = *(const bf16x8*)(Bhp + bo);
        bf16x8 bl = *(const bf16x8*)(Blp + bo);
        #pragma unroll
        for (int fm=0;fm<4;fm++){
          acc[fm][fn] = __builtin_amdgcn_mfma_f32_16x16x32_bf16(ah[fm], bh, acc[fm][fn], 0,0,0);
          acc[fm][fn] = __builtin_amdgcn_mfma_f32_16x16x32_bf16(ah[fm], bl, acc[fm][fn], 0,0,0);
          acc[fm][fn] = __builtin_amdgcn_mfma_f32_16x16x32_bf16(al[fm], bh, acc[fm][fn], 0,0,0);
        }
      }
    }
    __syncthreads();
  }
  int wrow = wr*64, wcol = wc*64;
  float bcol[4];
  #pragma unroll
  for (int fn=0;fn<4;fn++) bcol[fn] = bias[cb + wcol + fn*16 + lr];
  int cchunk = blockIdx.x*2 + wc;
  #pragma unroll
  for (int fm=0;fm<4;fm++){
    #pragma unroll
    for (int r=0;r<4;r++){
      int rowg = rb + wrow + fm*16 + kq*4 + r;
      float v0 = acc[fm][0][r] + bcol[0];
      float v1 = acc[fm][1][r] + bcol[1];
      float v2 = acc[fm][2][r] + bcol[2];
      float v3 = acc[fm][3][r] + bcol[3];
      size_t obase = (size_t)rowg*8192 + cb + wcol + lr;
      C[obase]      = v0;
      C[obase+16]   = v1;
      C[obase+32]   = v2;
      C[obase+48]   = v3;
      float m = fmaxf(fmaxf(v0,v1),fmaxf(v2,v3));
      #pragma unroll
      for (int mk=1;mk<16;mk<<=1) m = fmaxf(m, __shfl_xor(m, mk, 64));
      float s = __expf(v0-m)+__expf(v1-m)+__expf(v2-m)+__expf(v3-m);
      #pragma unroll
      for (int mk=1;mk<16;mk<<=1) s += __shfl_xor(s, mk, 64);
      if (lr==0){
        size_t pb = ((size_t)cchunk*NN + rowg)*2;
        pstats[pb]   = m;
        pstats[pb+1] = s;
      }
    }
  }
}

__global__ void k_lsmfin(const float* __restrict__ ps, float* __restrict__ lg) {
  int row = blockIdx.x*256 + threadIdx.x;
  float M = -INFINITY, S = 0.f;
  for (int c=0;c<128;c++){
    size_t pb = ((size_t)c*NN + row)*2;
    float m = ps[pb], s = ps[pb+1];
    if (m > M){ S = S*__expf(M-m) + s; M = m; }
    else S += s*__expf(m-M);
  }
  lg[row] = M + logf(S);
}

__global__ void k_lsub(float* __restrict__ C, const float* __restrict__ lg) {
  int i = blockIdx.x*256 + threadIdx.x;
  float4 v = ((float4*)C)[i];
  float L = lg[i>>11];
  v.x-=L; v.y-=L; v.z-=L; v.w-=L;
  ((float4*)C)[i] = v;
}

extern "C" void kernel_launch(void* const* d_in, const int* in_sizes, int n_in,
                              void* d_out, int out_size, void* d_ws, size_t ws_size,
                              hipStream_t stream) {
  (void)in_sizes; (void)n_in; (void)out_size; (void)ws_size;
  const float* x0     = (const float*)d_in[0];
  const int*   ei     = (const int*)d_in[1];
  const float* pseudo = (const float*)d_in[2];
  const float* W[6]; const float* R[6]; const float* Bb[6];
  for (int l=0;l<6;l++){
    W[l]=(const float*)d_in[3+3*l];
    R[l]=(const float*)d_in[4+3*l];
    Bb[l]=(const float*)d_in[5+3*l];
  }
  const float* L1w=(const float*)d_in[21];
  const float* L1b=(const float*)d_in[22];
  const float* L2w=(const float*)d_in[23];
  const float* L2b=(const float*)d_in[24];
  float* out = (float*)d_out;
  char* ws = (char*)d_ws;

  size_t off=0;
  auto alloc=[&](size_t bytes)->void*{
    size_t o=off; off += (bytes+511)&~511ULL; return (void*)(ws+o);
  };
  float* basis =(float*)alloc((size_t)NE*8*4);
  int*   kidx  =(int*)  alloc((size_t)NE*8*4);
  int*   sorted=(int*)  alloc((size_t)NE*4);
  int*   counts=(int*)  alloc((size_t)NN*4);
  int*   offs  =(int*)  alloc((size_t)(NN+1)*4);
  int*   cursor=(int*)  alloc((size_t)NN*4);
  int*   pcnt  =(int*)  alloc((size_t)8000*4);
  int*   poff  =(int*)  alloc((size_t)8001*4);
  int*   pcur  =(int*)  alloc((size_t)8001*4);
  uint2* pairs =(uint2*)alloc((size_t)NE*8*8);
  float* M1    =(float*)alloc((size_t)NN*128*4);
  unsigned short* Whi=(unsigned short*)alloc((size_t)NKT*64*64*2);
  unsigned short* Wlo=(unsigned short*)alloc((size_t)NKT*64*64*2);
  float* hA    =(float*)alloc((size_t)NN*64*4);
  float* hB    =(float*)alloc((size_t)NN*64*4);
  float* h2    =(float*)alloc((size_t)NN*256*4);
  float* croot =(float*)alloc((size_t)NN*64*4);
  float* cpart =(float*)alloc((size_t)8*NN*64*4);
  float* pstats=(float*)alloc((size_t)128*NN*2*4);
  float* lg    =(float*)alloc((size_t)NN*4);

  const int* src = ei;
  const int* dst = ei + NE;

  hipMemsetAsync(counts, 0, NN*4, stream);
  hipMemsetAsync(pcnt, 0, 8000*4, stream);
  k_basis<<<NE/256,256,0,stream>>>(pseudo,basis,kidx);
  k_hist <<<NE/256,256,0,stream>>>(dst,counts);
  k_scan <<<1,1024,0,stream>>>(counts,offs,cursor);
  k_place<<<NE/256,256,0,stream>>>(dst,cursor,sorted);
  k_phist<<<NE/256,256,0,stream>>>(dst,kidx,pcnt);
  k_pscan<<<1,1024,0,stream>>>(pcnt,poff,pcur);
  k_pplace<<<NE/256,256,0,stream>>>(src,dst,basis,kidx,pcur,pairs);

  dim3 gf(64, 8);
  // layer 1: 1 -> 32 (old path; tiny)
  k_build<1><<<NN,256,0,stream>>>(x0,basis,kidx,src,sorted,offs,M1,128);
  k_root<1,32><<<NN,32,0,stream>>>(x0,R[0],Bb[0],croot);
  k_gconv<32><<<gf,256,0,stream>>>(M1,W[0],cpart,125,128,8);
  k_reduce<<<(NN*32)/256,256,0,stream>>>(croot,cpart,hA,NN*32,8);
  // layer 2: 32 -> 64 (fused)
  k_wprep<32><<<NKT,256,0,stream>>>(W[1],Whi,Wlo);
  k_root<32,64><<<NN,64,0,stream>>>(hA,R[1],Bb[1],croot);
  k_fconv<32><<<gf,256,0,stream>>>(hA,Whi,Wlo,pairs,poff,cpart);
  k_reduce<<<(NN*64)/256,256,0,stream>>>(croot,cpart,hB,NN*64,8);
  // layers 3..6: 64 -> 64 (fused)
  float* hin=hB; float* hout=hA;
  for (int l=2;l<6;l++){
    k_wprep<64><<<NKT,256,0,stream>>>(W[l],Whi,Wlo);
    k_root<64,64><<<NN,64,0,stream>>>(hin,R[l],Bb[l],croot);
    k_fconv<64><<<gf,256,0,stream>>>(hin,Whi,Wlo,pairs,poff,cpart);
    k_reduce<<<(NN*64)/256,256,0,stream>>>(croot,cpart,hout,NN*64,8);
    float* tmp=hin; hin=hout; hout=tmp;
  }
  k_l1<<<NN,256,0,stream>>>(hin,L1w,L1b,h2);
  dim3 g2(64,64);
  k_l2m<<<g2,256,0,stream>>>(h2,L2w,L2b,out,pstats);
  k_lsmfin<<<NN/256,256,0,stream>>>(pstats,lg);
  k_lsub<<<(NN*8192/4)/256,256,0,stream>>>(out,lg);
}

// Round 4
// 2735.402 us; speedup vs baseline: 1.0647x; 1.0647x over previous
//
#include <hip/hip_runtime.h>
#include <math.h>

#define NN 8192
#define NE 131072
#define NKT 125
#define NT  126      // 125 spline tiles + 1 root tile
#define NRB 128      // row blocks of 64 rows
#define NB  (NRB*NT) // pair buckets
#define NSL 16       // K-slices for fused conv

typedef __attribute__((ext_vector_type(8))) short bf16x8;
typedef __attribute__((ext_vector_type(4))) float f32x4;

__device__ inline unsigned short bf16rne(float v){
  unsigned u = __float_as_uint(v);
  u += 0x7FFF + ((u>>16)&1);
  return (unsigned short)(u>>16);
}

__device__ inline void splitpack8(const f32x4& a0, const f32x4& a1, bf16x8& h, bf16x8& l){
  #pragma unroll
  for (int u=0;u<4;u++){
    unsigned short hh = bf16rne(a0[u]);
    h[u] = (short)hh;
    l[u] = (short)bf16rne(a0[u] - __uint_as_float((unsigned)hh<<16));
  }
  #pragma unroll
  for (int u=0;u<4;u++){
    unsigned short hh = bf16rne(a1[u]);
    h[u+4] = (short)hh;
    l[u+4] = (short)bf16rne(a1[u] - __uint_as_float((unsigned)hh<<16));
  }
}

// ---------------- basis ----------------
__global__ void k_basis(const float* __restrict__ pseudo,
                        float* __restrict__ basis, int* __restrict__ kidx) {
  int e = blockIdx.x * 256 + threadIdx.x;
  if (e >= NE) return;
  float s0 = pseudo[e*3+0]*4.f, s1 = pseudo[e*3+1]*4.f, s2 = pseudo[e*3+2]*4.f;
  float f0 = floorf(s0), f1 = floorf(s1), f2 = floorf(s2);
  int l0=(int)f0, l1=(int)f1, l2=(int)f2;
  float r0=s0-f0, r1=s1-f1, r2=s2-f2;
  #pragma unroll
  for (int s=0;s<8;s++){
    int b0=s&1, b1=(s>>1)&1, b2=(s>>2)&1;
    int i0=min(max(l0+b0,0),4);
    int i1=min(max(l1+b1,0),4);
    int i2=min(max(l2+b2,0),4);
    float w=(b0? r0:1.f-r0)*(b1? r1:1.f-r1)*(b2? r2:1.f-r2);
    basis[e*8+s]=w;
    kidx[e*8+s]=i0+5*i1+25*i2;
  }
}

// ---------------- counting sort by dst (layer-1 path) ----------------
__global__ void k_hist(const int* __restrict__ dst, int* __restrict__ counts) {
  int e = blockIdx.x*256 + threadIdx.x;
  if (e >= NE) return;
  atomicAdd(&counts[dst[e]], 1);
}

__global__ void k_scan(const int* __restrict__ counts, int* __restrict__ offs,
                       int* __restrict__ cursor) {
  __shared__ int lds[1024];
  int t = threadIdx.x;
  int base = t*8;
  int c[8]; int s = 0;
  #pragma unroll
  for (int j=0;j<8;j++){ c[j]=counts[base+j]; s+=c[j]; }
  lds[t]=s; __syncthreads();
  for (int o=1;o<1024;o<<=1){
    int v = (t>=o)? lds[t-o] : 0;
    __syncthreads();
    lds[t]+=v;
    __syncthreads();
  }
  int run = (t==0)? 0 : lds[t-1];
  #pragma unroll
  for (int j=0;j<8;j++){ offs[base+j]=run; cursor[base+j]=run; run+=c[j]; }
  if (t==1023) offs[NN]=run;
}

__global__ void k_place(const int* __restrict__ dst, int* __restrict__ cursor,
                        int* __restrict__ sorted) {
  int e = blockIdx.x*256 + threadIdx.x;
  if (e >= NE) return;
  int p = atomicAdd(&cursor[dst[e]], 1);
  sorted[p] = e;
}

// ---------------- pair sort by (dst>>6, tile): NB buckets ----------------
__global__ void k_scnt(int* __restrict__ cnt){
  int rb = threadIdx.x;
  if (rb < NRB) cnt[rb*NT + NKT] = 64;   // self bucket: one pair per row
}

__global__ void k_phist(const int* __restrict__ dst, const int* __restrict__ kidx,
                        int* __restrict__ cnt){
  int e = blockIdx.x*256 + threadIdx.x;
  if (e>=NE) return;
  int kb = (dst[e]>>6)*NT;
  #pragma unroll
  for (int c=0;c<8;c++) atomicAdd(&cnt[kb + kidx[e*8+c]], 1);
}

__global__ void k_pscan(const int* __restrict__ cnt, int* __restrict__ offs,
                        int* __restrict__ cur){
  __shared__ int lds[1024];
  int t=threadIdx.x, base=t*16;
  int c[16]; int s=0;
  #pragma unroll
  for (int j=0;j<16;j++){ int v=(base+j<NB)? cnt[base+j]:0; c[j]=v; s+=v; }
  lds[t]=s; __syncthreads();
  for (int o=1;o<1024;o<<=1){
    int v=(t>=o)?lds[t-o]:0;
    __syncthreads();
    lds[t]+=v;
    __syncthreads();
  }
  int run=(t==0)?0:lds[t-1];
  #pragma unroll
  for (int j=0;j<16;j++){
    if (base+j<=NB){ offs[base+j]=run; cur[base+j]=run; }
    run+=c[j];
  }
}

__global__ void k_pplace(const int* __restrict__ src, const int* __restrict__ dst,
                         const float* __restrict__ basis, const int* __restrict__ kidx,
                         int* __restrict__ cur, uint2* __restrict__ pairs){
  int e = blockIdx.x*256 + threadIdx.x;
  if (e>=NE) return;
  int d = dst[e];
  unsigned a = (unsigned)src[e] | ((unsigned)(d&63)<<16);
  int kb = (d>>6)*NT;
  #pragma unroll
  for (int c=0;c<8;c++){
    int p = atomicAdd(&cur[kb + kidx[e*8+c]], 1);
    pairs[p] = make_uint2(a, __float_as_uint(basis[e*8+c]));
  }
}

__global__ void k_spplace(const int* __restrict__ offs, uint2* __restrict__ pairs){
  int n = blockIdx.x*256 + threadIdx.x;
  if (n>=NN) return;
  int p = offs[(n>>6)*NT + NKT] + (n&63);
  pairs[p] = make_uint2((unsigned)n | ((unsigned)(n&63)<<16), __float_as_uint(1.0f));
}

// ---------------- W prep: [CIN][64] tiles -> transposed split bf16 [64][CIN] ----
template<int CIN>
__global__ void k_wprep(const float* __restrict__ W, unsigned short* __restrict__ Whi,
                        unsigned short* __restrict__ Wlo, int koff){
  int kb = blockIdx.x; int t = threadIdx.x;
  const float* Wk = W + (size_t)kb*CIN*64;
  unsigned short* Hk = Whi + (size_t)(kb+koff)*64*CIN;
  unsigned short* Lk = Wlo + (size_t)(kb+koff)*64*CIN;
  for (int idx=t; idx<CIN*64; idx+=256){
    int o = idx/CIN, i = idx - o*CIN;
    float v = Wk[i*64 + o];
    unsigned short h = bf16rne(v);
    Hk[idx] = h;
    Lk[idx] = bf16rne(v - __uint_as_float((unsigned)h<<16));
  }
}

// ---------------- fused scatter+GEMM conv (incl. root as tile 125) --------------
// grid (NRB=128 row-blocks of 64, NSL=16 tile-slices of 8). LDS fp32 tile
// [64][TK] swizzled; 4-deep pipelined pair accumulation; split-bf16 MFMA.
template<int TK>   // TK == CIN in {32,64}
__global__ __launch_bounds__(256) void k_fconv(const float* __restrict__ x,
    const unsigned short* __restrict__ Whi, const unsigned short* __restrict__ Wlo,
    const uint2* __restrict__ pairs, const int* __restrict__ poff,
    float* __restrict__ Cp) {
  constexpr int KK = TK/32;
  __shared__ float Afp[64*TK];
  int t = threadIdx.x, w = t>>6, lane = t&63;
  int lr = lane&15, kq = lane>>4;
  int rb = blockIdx.x;
  int s  = blockIdx.y;
  int t0 = s*8, t1 = min(NT, t0+8);
  int wrow = w*16;

  f32x4 acc[4];
  #pragma unroll
  for (int j=0;j<4;j++) acc[j] = (f32x4){0.f,0.f,0.f,0.f};

  for (int tile=t0; tile<t1; ++tile) {
    // zero the fp32 accumulation tile
    #pragma unroll
    for (int q=0;q<(64*TK)/(4*256);q++)
      *(f32x4*)&Afp[(t + q*256)*4] = (f32x4){0.f,0.f,0.f,0.f};
    // W fragments (L2-resident), issued before the barrier
    bf16x8 wh[KK][4], wl[KK][4];
    const unsigned short* wb  = Whi + (size_t)tile*64*TK;
    const unsigned short* wlb = Wlo + (size_t)tile*64*TK;
    #pragma unroll
    for (int kk=0;kk<KK;kk++)
      #pragma unroll
      for (int fn=0;fn<4;fn++){
        int off = (fn*16+lr)*TK + kk*32 + kq*8;
        wh[kk][fn] = *(const bf16x8*)(wb + off);
        wl[kk][fn] = *(const bf16x8*)(wlb + off);
      }
    __syncthreads();
    // pair accumulation, 4-deep pipeline
    int bkey = rb*NT + tile;
    int r0 = poff[bkey], r1 = poff[bkey+1];
    if constexpr (TK==64) {
      int j = r0 + w;
      for (; j + 12 < r1; j += 16) {
        uint2 p0=pairs[j], p1=pairs[j+4], p2=pairs[j+8], p3=pairs[j+12];
        float x0 = x[(p0.x&0xffff)*64 + lane];
        float x1 = x[(p1.x&0xffff)*64 + lane];
        float x2 = x[(p2.x&0xffff)*64 + lane];
        float x3 = x[(p3.x&0xffff)*64 + lane];
        int q0=(p0.x>>16)&63, q1=(p1.x>>16)&63, q2=(p2.x>>16)&63, q3=(p3.x>>16)&63;
        atomicAdd(&Afp[(q0*64+lane)^((q0&7)<<2)], __uint_as_float(p0.y)*x0);
        atomicAdd(&Afp[(q1*64+lane)^((q1&7)<<2)], __uint_as_float(p1.y)*x1);
        atomicAdd(&Afp[(q2*64+lane)^((q2&7)<<2)], __uint_as_float(p2.y)*x2);
        atomicAdd(&Afp[(q3*64+lane)^((q3&7)<<2)], __uint_as_float(p3.y)*x3);
      }
      for (; j < r1; j += 4) {
        uint2 p = pairs[j];
        float xv = x[(p.x&0xffff)*64 + lane];
        int q=(p.x>>16)&63;
        atomicAdd(&Afp[(q*64+lane)^((q&7)<<2)], __uint_as_float(p.y)*xv);
      }
    } else {
      int ln = lane&31, half = lane>>5;
      int j = r0 + w*2 + half;
      for (; j + 24 < r1; j += 32) {
        uint2 p0=pairs[j], p1=pairs[j+8], p2=pairs[j+16], p3=pairs[j+24];
        float x0 = x[(p0.x&0xffff)*32 + ln];
        float x1 = x[(p1.x&0xffff)*32 + ln];
        float x2 = x[(p2.x&0xffff)*32 + ln];
        float x3 = x[(p3.x&0xffff)*32 + ln];
        int q0=(p0.x>>16)&63, q1=(p1.x>>16)&63, q2=(p2.x>>16)&63, q3=(p3.x>>16)&63;
        atomicAdd(&Afp[(q0*32+ln)^((q0&7)<<2)], __uint_as_float(p0.y)*x0);
        atomicAdd(&Afp[(q1*32+ln)^((q1&7)<<2)], __uint_as_float(p1.y)*x1);
        atomicAdd(&Afp[(q2*32+ln)^((q2&7)<<2)], __uint_as_float(p2.y)*x2);
        atomicAdd(&Afp[(q3*32+ln)^((q3&7)<<2)], __uint_as_float(p3.y)*x3);
      }
      for (; j < r1; j += 8) {
        uint2 p = pairs[j];
        float xv = x[(p.x&0xffff)*32 + ln];
        int q=(p.x>>16)&63;
        atomicAdd(&Afp[(q*32+ln)^((q&7)<<2)], __uint_as_float(p.y)*xv);
      }
    }
    __syncthreads();
    // MFMA: split-bf16 A from LDS, W from regs
    #pragma unroll
    for (int kk=0;kk<KK;kk++){
      int row = wrow + lr;
      int e0 = row*TK + kk*32 + kq*8;
      int sz = (row&7)<<2;
      f32x4 a0 = *(const f32x4*)&Afp[(e0  )^sz];
      f32x4 a1 = *(const f32x4*)&Afp[(e0+4)^sz];
      bf16x8 ah, al;
      splitpack8(a0, a1, ah, al);
      #pragma unroll
      for (int fn=0;fn<4;fn++){
        acc[fn] = __builtin_amdgcn_mfma_f32_16x16x32_bf16(ah, wh[kk][fn], acc[fn], 0,0,0);
        acc[fn] = __builtin_amdgcn_mfma_f32_16x16x32_bf16(ah, wl[kk][fn], acc[fn], 0,0,0);
        acc[fn] = __builtin_amdgcn_mfma_f32_16x16x32_bf16(al, wh[kk][fn], acc[fn], 0,0,0);
      }
    }
    __syncthreads();
  }
  // epilogue: split-K partials
  size_t sbase = (size_t)s*NN*64;
  #pragma unroll
  for (int fn=0;fn<4;fn++)
    #pragma unroll
    for (int r=0;r<4;r++){
      int row = rb*64 + wrow + kq*4 + r;
      Cp[sbase + (size_t)row*64 + fn*16 + lr] = acc[fn][r];
    }
}

// ---------------- build M rows, layer 1 only ----------------
template<int CIN>
__global__ void k_build(const float* __restrict__ x,
                        const float* __restrict__ basis, const int* __restrict__ kidx,
                        const int* __restrict__ src, const int* __restrict__ sorted,
                        const int* __restrict__ offs, float* __restrict__ M, int lda) {
  constexpr int SZ = NKT*CIN;
  __shared__ float acc[SZ];
  int n = blockIdx.x, t = threadIdx.x;
  for (int i=t;i<SZ;i+=256) acc[i]=0.f;
  __syncthreads();
  int beg = offs[n], end = offs[n+1];
  int wv = t>>6, ln = t&63;
  for (int j=beg+wv; j<end; j+=4) {
    int e = sorted[j];
    int sv = src[e];
    float xv = (ln<CIN)? x[(size_t)sv*CIN+ln] : 0.f;
    #pragma unroll
    for (int c=0;c<8;c++){
      float b = basis[e*8+c];
      int k = kidx[e*8+c];
      if (ln<CIN) atomicAdd(&acc[k*CIN+ln], b*xv);
    }
  }
  __syncthreads();
  size_t base = (size_t)n*lda;
  for (int i=t;i<lda;i+=256) M[base+i] = (i<SZ)? acc[i] : 0.f;
}

// ---------------- root weight + bias (layer 1 only) ----------------
template<int CIN,int COUT>
__global__ void k_root(const float* __restrict__ x, const float* __restrict__ R,
                       const float* __restrict__ B, float* __restrict__ C) {
  int n = blockIdx.x, o = threadIdx.x;
  float s = B[o];
  #pragma unroll 8
  for (int i=0;i<CIN;i++) s += x[(size_t)n*CIN+i]*R[i*COUT+o];
  C[(size_t)n*COUT+o] = s;
}

// ---------------- conv GEMM (layer 1 only), split-bf16 MFMA ----------------
template<int BN>
__global__ __launch_bounds__(256) void k_gconv(const float* __restrict__ A,
                                               const float* __restrict__ B,
                                               float* __restrict__ Cp,
                                               int K, int lda, int nsl) {
  __shared__ alignas(16) char smem[2*128*128 + 2*BN*128];
  char* Ahp = smem;
  char* Alp = smem + 128*128;
  char* Bhp = smem + 2*128*128;
  char* Blp = Bhp + BN*128;

  int t = threadIdx.x;
  int w = t>>6, lane = t&63;
  int lr = lane & 15, kq = lane >> 4;
  int rb = blockIdx.x*128;
  int sl = blockIdx.y;
  int len = ((K + nsl - 1)/nsl + 63) & ~63;
  int kbeg = sl*len;
  int kend = min(K, kbeg + len);

  f32x4 acc[2][BN/16];
  #pragma unroll
  for (int i=0;i<2;i++)
    #pragma unroll
    for (int j=0;j<BN/16;j++) acc[i][j] = (f32x4){0.f,0.f,0.f,0.f};

  for (int k0 = kbeg; k0 < kend; k0 += 64) {
    #pragma unroll
    for (int q=0;q<8;q++){
      int lin = t + 256*q;
      int row = lin >> 4;
      int f4  = lin & 15;
      int kg = k0 + f4*4;
      const float* ap = A + (size_t)(rb+row)*lda + kg;
      float4 v; v.x=0.f; v.y=0.f; v.z=0.f; v.w=0.f;
      if (kg + 3 < kend) v = *(const float4*)ap;
      else {
        if (kg   < kend) v.x = ap[0];
        if (kg+1 < kend) v.y = ap[1];
        if (kg+2 < kend) v.z = ap[2];
      }
      unsigned short h[4], l[4];
      float vv[4] = {v.x, v.y, v.z, v.w};
      #pragma unroll
      for (int u=0;u<4;u++){
        unsigned short hh = bf16rne(vv[u]);
        float fh = __uint_as_float(((unsigned)hh)<<16);
        h[u]=hh; l[u]=bf16rne(vv[u]-fh);
      }
      int bo = (row*128 + f4*8) ^ ((row&7)<<4);
      *(uint2*)(Ahp + bo) = make_uint2((unsigned)h[0]|((unsigned)h[1]<<16),
                                       (unsigned)h[2]|((unsigned)h[3]<<16));
      *(uint2*)(Alp + bo) = make_uint2((unsigned)l[0]|((unsigned)l[1]<<16),
                                       (unsigned)l[2]|((unsigned)l[3]<<16));
    }
    constexpr int BITER = (64*(BN/4))/256;
    #pragma unroll
    for (int q=0;q<BITER;q++){
      int lin = t + 256*q;
      int kr = lin / (BN/4);
      int c4 = (lin % (BN/4))*4;
      int kg = k0 + kr;
      float4 v; v.x=0.f; v.y=0.f; v.z=0.f; v.w=0.f;
      if (kg < kend) v = *(const float4*)&B[(size_t)kg*BN + c4];
      float vv[4] = {v.x, v.y, v.z, v.w};
      #pragma unroll
      for (int u=0;u<4;u++){
        int n = c4 + u;
        unsigned short hh = bf16rne(vv[u]);
        float fh = __uint_as_float(((unsigned)hh)<<16);
        int bo = (n*128 + kr*2) ^ ((n&7)<<4);
        *(unsigned short*)(Bhp + bo) = hh;
        *(unsigned short*)(Blp + bo) = bf16rne(vv[u]-fh);
      }
    }
    __syncthreads();
    int wrow = w*32;
    #pragma unroll
    for (int kk=0;kk<2;kk++){
      int kbyte = (kk*32 + kq*8)*2;
      bf16x8 ah[2], al[2];
      #pragma unroll
      for (int fm=0;fm<2;fm++){
        int row = wrow + fm*16 + lr;
        int bo = (row*128 + kbyte) ^ ((row&7)<<4);
        ah[fm] = *(const bf16x8*)(Ahp + bo);
        al[fm] = *(const bf16x8*)(Alp + bo);
      }
      #pragma unroll
      for (int fn=0;fn<BN/16;fn++){
        int n = fn*16 + lr;
        int bo = (n*128 + kbyte) ^ ((n&7)<<4);
        bf16x8 bh = *(const bf16x8*)(Bhp + bo);
        bf16x8 bl = *(const bf16x8*)(Blp + bo);
        #pragma unroll
        for (int fm=0;fm<2;fm++){
          acc[fm][fn] = __builtin_amdgcn_mfma_f32_16x16x32_bf16(ah[fm], bh, acc[fm][fn], 0,0,0);
          acc[fm][fn] = __builtin_amdgcn_mfma_f32_16x16x32_bf16(ah[fm], bl, acc[fm][fn], 0,0,0);
          acc[fm][fn] = __builtin_amdgcn_mfma_f32_16x16x32_bf16(al[fm], bh, acc[fm][fn], 0,0,0);
        }
      }
    }
    __syncthreads();
  }
  size_t sbase = (size_t)sl * NN * BN;
  int r0g = rb + w*32;
  #pragma unroll
  for (int fm=0;fm<2;fm++)
    #pragma unroll
    for (int fn=0;fn<BN/16;fn++)
      #pragma unroll
      for (int r=0;r<4;r++){
        int row = r0g + fm*16 + kq*4 + r;
        int col = fn*16 + lr;
        Cp[sbase + (size_t)row*BN + col] = acc[fm][fn][r];
      }
}

// ---------------- reduce split-K partials + croot, ELU (layer 1) ----------------
__global__ void k_reduce(const float* __restrict__ Cr, const float* __restrict__ Cp,
                         float* __restrict__ H, int total, int nsl) {
  int i = blockIdx.x*256 + threadIdx.x;
  if (i >= total) return;
  float v = Cr[i];
  for (int s=0;s<nsl;s++) v += Cp[(size_t)s*total+i];
  H[i] = v>0.f ? v : expm1f(v);
}

// ---------------- reduce split-K partials + bias, ELU (fused layers) ------------
__global__ void k_reduce2(const float* __restrict__ Cp, const float* __restrict__ B,
                          float* __restrict__ H, int total) {
  int i = blockIdx.x*256 + threadIdx.x;
  if (i >= total) return;
  float v = B[i & 63];
  #pragma unroll
  for (int s=0;s<NSL;s++) v += Cp[(size_t)s*total+i];
  H[i] = v>0.f ? v : expm1f(v);
}

// ---------------- Linear(64,256) + ELU ----------------
__global__ void k_l1(const float* __restrict__ H, const float* __restrict__ Wm,
                     const float* __restrict__ b, float* __restrict__ O) {
  int n = blockIdx.x, o = threadIdx.x;
  float s = b[o];
  #pragma unroll 16
  for (int i=0;i<64;i++) s += H[(size_t)n*64+i]*Wm[i*256+o];
  s = s>0.f ? s : expm1f(s);
  O[(size_t)n*256+o] = s;
}

// ---------------- Linear(256,8192) split-bf16 MFMA + bias + lsm stats ----------
__global__ __launch_bounds__(256) void k_l2m(const float* __restrict__ A,
                                             const float* __restrict__ B,
                                             const float* __restrict__ bias,
                                             float* __restrict__ C,
                                             float* __restrict__ pstats) {
  __shared__ alignas(16) char smem[4*128*128];
  char* Ahp = smem;
  char* Alp = smem + 128*128;
  char* Bhp = smem + 2*128*128;
  char* Blp = smem + 3*128*128;

  int t = threadIdx.x;
  int w = t>>6, lane = t&63;
  int lr = lane & 15, kq = lane >> 4;
  int wr = w>>1, wc = w&1;
  int rb = blockIdx.y*128;
  int cb = blockIdx.x*128;

  f32x4 acc[4][4];
  #pragma unroll
  for (int i=0;i<4;i++)
    #pragma unroll
    for (int j=0;j<4;j++) acc[i][j] = (f32x4){0.f,0.f,0.f,0.f};

  for (int k0=0;k0<256;k0+=64) {
    #pragma unroll
    for (int q=0;q<8;q++){
      int lin = t + 256*q;
      int row = lin >> 4;
      int f4  = lin & 15;
      const float4 v = *(const float4*)&A[(size_t)(rb+row)*256 + k0 + f4*4];
      unsigned short h[4], l[4];
      float vv[4] = {v.x, v.y, v.z, v.w};
      #pragma unroll
      for (int u=0;u<4;u++){
        unsigned short hh = bf16rne(vv[u]);
        float fh = __uint_as_float(((unsigned)hh)<<16);
        h[u]=hh; l[u]=bf16rne(vv[u]-fh);
      }
      int bo = (row*128 + f4*8) ^ ((row&7)<<4);
      *(uint2*)(Ahp + bo) = make_uint2((unsigned)h[0]|((unsigned)h[1]<<16),
                                       (unsigned)h[2]|((unsigned)h[3]<<16));
      *(uint2*)(Alp + bo) = make_uint2((unsigned)l[0]|((unsigned)l[1]<<16),
                                       (unsigned)l[2]|((unsigned)l[3]<<16));
    }
    #pragma unroll
    for (int q=0;q<8;q++){
      int lin = t + 256*q;
      int kr = lin >> 5;
      int c4 = (lin & 31)*4;
      const float4 v = *(const float4*)&B[(size_t)(k0+kr)*8192 + cb + c4];
      float vv[4] = {v.x, v.y, v.z, v.w};
      #pragma unroll
      for (int u=0;u<4;u++){
        int n = c4 + u;
        unsigned short hh = bf16rne(vv[u]);
        float fh = __uint_as_float(((unsigned)hh)<<16);
        int bo = (n*128 + kr*2) ^ ((n&7)<<4);
        *(unsigned short*)(Bhp + bo) = hh;
        *(unsigned short*)(Blp + bo) = bf16rne(vv[u]-fh);
      }
    }
    __syncthreads();
    int wrow = wr*64, wcol = wc*64;
    #pragma unroll
    for (int kk=0;kk<2;kk++){
      int kbyte = (kk*32 + kq*8)*2;
      bf16x8 ah[4], al[4];
      #pragma unroll
      for (int fm=0;fm<4;fm++){
        int row = wrow + fm*16 + lr;
        int bo = (row*128 + kbyte) ^ ((row&7)<<4);
        ah[fm] = *(const bf16x8*)(Ahp + bo);
        al[fm] = *(const bf16x8*)(Alp + bo);
      }
      #pragma unroll
      for (int fn=0;fn<4;fn++){
        int n = wcol + fn*16 + lr;
        int bo = (n*128 + kbyte) ^ ((n&7)<<4);
        bf16x8 bh = *(const bf16x8*)(Bhp + bo);
        bf16x8 bl = *(const bf16x8*)(Blp + bo);
        #pragma unroll
        for (int fm=0;fm<4;fm++){
          acc[fm][fn] = __builtin_amdgcn_mfma_f32_16x16x32_bf16(ah[fm], bh, acc[fm][fn], 0,0,0);
          acc[fm][fn] = __builtin_amdgcn_mfma_f32_16x16x32_bf16(ah[fm], bl, acc[fm][fn], 0,0,0);
          acc[fm][fn] = __builtin_amdgcn_mfma_f32_16x16x32_bf16(al[fm], bh, acc[fm][fn], 0,0,0);
        }
      }
    }
    __syncthreads();
  }
  int wrow = wr*64, wcol = wc*64;
  float bcol[4];
  #pragma unroll
  for (int fn=0;fn<4;fn++) bcol[fn] = bias[cb + wcol + fn*16 + lr];
  int cchunk = blockIdx.x*2 + wc;
  #pragma unroll
  for (int fm=0;fm<4;fm++){
    #pragma unroll
    for (int r=0;r<4;r++){
      int rowg = rb + wrow + fm*16 + kq*4 + r;
      float v0 = acc[fm][0][r] + bcol[0];
      float v1 = acc[fm][1][r] + bcol[1];
      float v2 = acc[fm][2][r] + bcol[2];
      float v3 = acc[fm][3][r] + bcol[3];
      size_t obase = (size_t)rowg*8192 + cb + wcol + lr;
      C[obase]      = v0;
      C[obase+16]   = v1;
      C[obase+32]   = v2;
      C[obase+48]   = v3;
      float m = fmaxf(fmaxf(v0,v1),fmaxf(v2,v3));
      #pragma unroll
      for (int mk=1;mk<16;mk<<=1) m = fmaxf(m, __shfl_xor(m, mk, 64));
      float s = __expf(v0-m)+__expf(v1-m)+__expf(v2-m)+__expf(v3-m);
      #pragma unroll
      for (int mk=1;mk<16;mk<<=1) s += __shfl_xor(s, mk, 64);
      if (lr==0){
        size_t pb = ((size_t)cchunk*NN + rowg)*2;
        pstats[pb]   = m;
        pstats[pb+1] = s;
      }
    }
  }
}

__global__ void k_lsmfin(const float* __restrict__ ps, float* __restrict__ lg) {
  int row = blockIdx.x*256 + threadIdx.x;
  float M = -INFINITY, S = 0.f;
  for (int c=0;c<128;c++){
    size_t pb = ((size_t)c*NN + row)*2;
    float m = ps[pb], s = ps[pb+1];
    if (m > M){ S = S*__expf(M-m) + s; M = m; }
    else S += s*__expf(m-M);
  }
  lg[row] = M + logf(S);
}

__global__ void k_lsub(float* __restrict__ C, const float* __restrict__ lg) {
  int i = blockIdx.x*256 + threadIdx.x;
  float4 v = ((float4*)C)[i];
  float L = lg[i>>11];
  v.x-=L; v.y-=L; v.z-=L; v.w-=L;
  ((float4*)C)[i] = v;
}

extern "C" void kernel_launch(void* const* d_in, const int* in_sizes, int n_in,
                              void* d_out, int out_size, void* d_ws, size_t ws_size,
                              hipStream_t stream) {
  (void)in_sizes; (void)n_in; (void)out_size; (void)ws_size;
  const float* x0     = (const float*)d_in[0];
  const int*   ei     = (const int*)d_in[1];
  const float* pseudo = (const float*)d_in[2];
  const float* W[6]; const float* R[6]; const float* Bb[6];
  for (int l=0;l<6;l++){
    W[l]=(const float*)d_in[3+3*l];
    R[l]=(const float*)d_in[4+3*l];
    Bb[l]=(const float*)d_in[5+3*l];
  }
  const float* L1w=(const float*)d_in[21];
  const float* L1b=(const float*)d_in[22];
  const float* L2w=(const float*)d_in[23];
  const float* L2b=(const float*)d_in[24];
  float* out = (float*)d_out;
  char* ws = (char*)d_ws;

  size_t off=0;
  auto alloc=[&](size_t bytes)->void*{
    size_t o=off; off += (bytes+511)&~511ULL; return (void*)(ws+o);
  };
  float* basis =(float*)alloc((size_t)NE*8*4);
  int*   kidx  =(int*)  alloc((size_t)NE*8*4);
  int*   sorted=(int*)  alloc((size_t)NE*4);
  int*   counts=(int*)  alloc((size_t)NN*4);
  int*   offs  =(int*)  alloc((size_t)(NN+1)*4);
  int*   cursor=(int*)  alloc((size_t)NN*4);
  int*   pcnt  =(int*)  alloc((size_t)NB*4);
  int*   poff  =(int*)  alloc((size_t)(NB+1)*4);
  int*   pcur  =(int*)  alloc((size_t)(NB+1)*4);
  uint2* pairs =(uint2*)alloc(((size_t)NE*8 + NN)*8);
  float* M1    =(float*)alloc((size_t)NN*128*4);
  unsigned short* Whi=(unsigned short*)alloc((size_t)NT*64*64*2);
  unsigned short* Wlo=(unsigned short*)alloc((size_t)NT*64*64*2);
  float* hA    =(float*)alloc((size_t)NN*64*4);
  float* hB    =(float*)alloc((size_t)NN*64*4);
  float* h2    =(float*)alloc((size_t)NN*256*4);
  float* croot =(float*)alloc((size_t)NN*64*4);
  float* pstats=(float*)alloc((size_t)128*NN*2*4);
  float* lg    =(float*)alloc((size_t)NN*4);
  float* cpart = out;   // d_out (256 MB) doubles as split-K partial scratch

  const int* src = ei;
  const int* dst = ei + NE;

  hipMemsetAsync(counts, 0, NN*4, stream);
  hipMemsetAsync(pcnt, 0, NB*4, stream);
  k_basis<<<NE/256,256,0,stream>>>(pseudo,basis,kidx);
  k_hist <<<NE/256,256,0,stream>>>(dst,counts);
  k_scan <<<1,1024,0,stream>>>(counts,offs,cursor);
  k_place<<<NE/256,256,0,stream>>>(dst,cursor,sorted);
  k_scnt <<<1,128,0,stream>>>(pcnt);
  k_phist<<<NE/256,256,0,stream>>>(dst,kidx,pcnt);
  k_pscan<<<1,1024,0,stream>>>(pcnt,poff,pcur);
  k_pplace<<<NE/256,256,0,stream>>>(src,dst,basis,kidx,pcur,pairs);
  k_spplace<<<NN/256,256,0,stream>>>(poff,pairs);

  dim3 gg(64, 8);
  dim3 gf(NRB, NSL);
  // layer 1: 1 -> 32 (M-based path; K=125 is tiny)
  k_build<1><<<NN,256,0,stream>>>(x0,basis,kidx,src,sorted,offs,M1,128);
  k_root<1,32><<<NN,32,0,stream>>>(x0,R[0],Bb[0],croot);
  k_gconv<32><<<gg,256,0,stream>>>(M1,W[0],cpart,125,128,8);
  k_reduce<<<(NN*32)/256,256,0,stream>>>(croot,cpart,hA,NN*32,8);
  // layer 2: 32 -> 64 (fused, root folded as tile 125)
  k_wprep<32><<<NKT,256,0,stream>>>(W[1],Whi,Wlo,0);
  k_wprep<32><<<1,256,0,stream>>>(R[1],Whi,Wlo,NKT);
  k_fconv<32><<<gf,256,0,stream>>>(hA,Whi,Wlo,pairs,poff,cpart);
  k_reduce2<<<(NN*64)/256,256,0,stream>>>(cpart,Bb[1],hB,NN*64);
  // layers 3..6: 64 -> 64 (fused)
  float* hin=hB; float* hout=hA;
  for (int l=2;l<6;l++){
    k_wprep<64><<<NKT,256,0,stream>>>(W[l],Whi,Wlo,0);
    k_wprep<64><<<1,256,0,stream>>>(R[l],Whi,Wlo,NKT);
    k_fconv<64><<<gf,256,0,stream>>>(hin,Whi,Wlo,pairs,poff,cpart);
    k_reduce2<<<(NN*64)/256,256,0,stream>>>(cpart,Bb[l],hout,NN*64);
    float* tmp=hin; hin=hout; hout=tmp;
  }
  k_l1<<<NN,256,0,stream>>>(hin,L1w,L1b,h2);
  dim3 g2(64,64);
  k_l2m<<<g2,256,0,stream>>>(h2,L2w,L2b,out,pstats);
  k_lsmfin<<<NN/256,256,0,stream>>>(pstats,lg);
  k_lsub<<<(NN*8192/4)/256,256,0,stream>>>(out,lg);
}